// Round 9
// baseline (9046.255 us; speedup 1.0000x reference)
//
#include <hip/hip_runtime.h>
#include <hip/hip_bf16.h>
#include <stdint.h>
#include <stddef.h>

// Problem sizes (fixed)
#define HID   1024
#define NB    64
#define SEQ   512
#define G3    3072   // 3*HID
#define EMB   512
#define LAT   64

typedef __attribute__((ext_vector_type(4))) float f32x4;
typedef __attribute__((ext_vector_type(8))) short bfrag;  // 8 bf16 (4 VGPRs)
typedef unsigned long long ull;

// ---------- helpers ----------
__device__ __forceinline__ unsigned short f2bf(float x) {   // RNE f32->bf16
  union { float f; unsigned u; } v; v.f = x;
  unsigned u = v.u + 0x7fffu + ((v.u >> 16) & 1u);
  return (unsigned short)(u >> 16);
}
__device__ __forceinline__ float bf2f(short s) {
  union { unsigned u; float f; } v; v.u = ((unsigned)(unsigned short)s) << 16;
  return v.f;
}
__device__ __forceinline__ float fsig(float x) {
  return 1.0f / (1.0f + __builtin_exp2f(-1.4426950408889634f * x));
}
__device__ __forceinline__ float ftanh(float x) {
  return 1.0f - 2.0f / (1.0f + __builtin_exp2f(2.8853900817779268f * x));
}
__device__ __forceinline__ void gload_lds16(const void* g, void* l) {
  __builtin_amdgcn_global_load_lds(
      (const __attribute__((address_space(1))) unsigned int*)g,
      (__attribute__((address_space(3))) unsigned int*)l, 16, 0, 0);
}

// ---------- kernel 0: w_ih f32 -> bf16 ----------
__global__ void cvt_wih_kernel(const float* __restrict__ in, short* __restrict__ out) {
  int i = (blockIdx.x * 256 + threadIdx.x) * 8;   // grid sized exactly
  f32x4 a = *(const f32x4*)(in + i);
  f32x4 b = *(const f32x4*)(in + i + 4);
  bfrag o;
  o[0]=(short)f2bf(a[0]); o[1]=(short)f2bf(a[1]); o[2]=(short)f2bf(a[2]); o[3]=(short)f2bf(a[3]);
  o[4]=(short)f2bf(b[0]); o[5]=(short)f2bf(b[1]); o[6]=(short)f2bf(b[2]); o[7]=(short)f2bf(b[3]);
  *(bfrag*)(out + i) = o;
}

// ---------- kernel 1: gx = emb[ids] @ w_ih^T  (bf16 MFMA, fp32 acc, bf16 out) ----------
__global__ void __launch_bounds__(256) gemm_gx_kernel(
    const int* __restrict__ ids, const float* __restrict__ emb,
    const short* __restrict__ wih, short* __restrict__ gx)
{
  const int nt = blockIdx.x, mt = blockIdx.y;
  const int tid = threadIdx.x;
  const int lane = tid & 63, wave = tid >> 6;
  const int wr = wave >> 1, wc = wave & 1;

  __shared__ __align__(16) short A_lds[128 * 48];
  __shared__ __align__(16) short B_lds[128 * 32];
  __shared__ int ids_s[128];

  if (tid < 128) ids_s[tid] = ids[mt * 128 + tid];
  __syncthreads();

  f32x4 acc[4][4];
  #pragma unroll
  for (int i = 0; i < 4; ++i)
    #pragma unroll
    for (int j = 0; j < 4; ++j) acc[i][j] = (f32x4){0.f, 0.f, 0.f, 0.f};

  const int r_stage = tid >> 1;
  const int kh = (tid & 1) * 16;

  #pragma unroll 1
  for (int kc = 0; kc < 16; ++kc) {
    __syncthreads();
    {
      const float* src = emb + (size_t)ids_s[r_stage] * 512 + kc * 32 + kh;
      f32x4 v0 = *(const f32x4*)(src);
      f32x4 v1 = *(const f32x4*)(src + 4);
      f32x4 v2 = *(const f32x4*)(src + 8);
      f32x4 v3 = *(const f32x4*)(src + 12);
      bfrag p0, p1;
      p0[0]=(short)f2bf(v0[0]); p0[1]=(short)f2bf(v0[1]); p0[2]=(short)f2bf(v0[2]); p0[3]=(short)f2bf(v0[3]);
      p0[4]=(short)f2bf(v1[0]); p0[5]=(short)f2bf(v1[1]); p0[6]=(short)f2bf(v1[2]); p0[7]=(short)f2bf(v1[3]);
      p1[0]=(short)f2bf(v2[0]); p1[1]=(short)f2bf(v2[1]); p1[2]=(short)f2bf(v2[2]); p1[3]=(short)f2bf(v2[3]);
      p1[4]=(short)f2bf(v3[0]); p1[5]=(short)f2bf(v3[1]); p1[6]=(short)f2bf(v3[2]); p1[7]=(short)f2bf(v3[3]);
      *(bfrag*)&A_lds[r_stage * 48 + kh]     = p0;
      *(bfrag*)&A_lds[r_stage * 48 + kh + 8] = p1;
    }
    {
      #pragma unroll
      for (int ii = 0; ii < 2; ++ii) {
        int i = wave * 2 + ii;
        const short* src = wih + (size_t)(nt * 128 + i * 16 + (lane >> 2)) * 512
                               + kc * 32 + (lane & 3) * 8;
        gload_lds16((const void*)src, (void*)&B_lds[i * 512]);
      }
    }
    asm volatile("s_waitcnt vmcnt(0)" ::: "memory");
    __syncthreads();

    bfrag a[4], b[4];
    #pragma unroll
    for (int mi = 0; mi < 4; ++mi)
      a[mi] = *(const bfrag*)&A_lds[(wr * 64 + mi * 16 + (lane & 15)) * 48 + (lane >> 4) * 8];
    #pragma unroll
    for (int ni = 0; ni < 4; ++ni)
      b[ni] = *(const bfrag*)&B_lds[(wc * 64 + ni * 16 + (lane & 15)) * 32 + (lane >> 4) * 8];
    #pragma unroll
    for (int mi = 0; mi < 4; ++mi)
      #pragma unroll
      for (int ni = 0; ni < 4; ++ni)
        acc[mi][ni] = __builtin_amdgcn_mfma_f32_16x16x32_bf16(a[mi], b[ni], acc[mi][ni], 0, 0, 0);
  }

  #pragma unroll
  for (int mi = 0; mi < 4; ++mi)
    #pragma unroll
    for (int ni = 0; ni < 4; ++ni)
      #pragma unroll
      for (int r = 0; r < 4; ++r) {
        int m = mt * 128 + wr * 64 + mi * 16 + (lane >> 4) * 4 + r;
        int n = nt * 128 + wc * 64 + ni * 16 + (lane & 15);
        gx[(size_t)m * G3 + n] = (short)f2bf(acc[mi][ni][r]);
      }
}

// ---------- kernel 2: persistent GRU scan — 4-team pipelined, comms wave ----------
// 64 WGs x 320 thr (waves 0-3 compute K-quarters, wave 4 = comms). WG cg owns
// 16 hidden cols for ALL 4 teams (16 batch rows each), rotating team slots
// within a step. Exchange (bf16, [team][b][cg][c4]) is flag/superflag gated:
// wave4 publishes+drains+flags (off compute path); WGs cg<4 aggregate their
// team's 64 flags into ONE superflag line that all consumers poll. h loads are
// issued 2 slots ahead into ping-pong reg buffers -> sync latency fully hidden.
__global__ void __launch_bounds__(320, 1) gru_scan_kernel(
    const short* __restrict__ gx, const float* __restrict__ whh,
    const float* __restrict__ bihp, const float* __restrict__ bhhp,
    ull* __restrict__ hbuf_q, unsigned* __restrict__ flags,
    unsigned* __restrict__ superf, float* __restrict__ hsum)
{
  const int cg   = blockIdx.x;             // 0..63 col-group
  const int tid  = threadIdx.x;            // 0..319
  const int lane = tid & 63, wave = tid >> 6;   // wave 0..3 compute, 4 comms
  const int bl   = lane & 15;
  const int bsub = (lane >> 4) * 4;
  const int jcol = cg * 16 + bl;

  __shared__ __align__(16) short h_lds[16 * 1024];     // 32KB [b][k] swizzled
  __shared__ __align__(16) float part[3 * 3 * 256];    // 9KB  [g][wave-1][lane*4]
  __shared__ __align__(16) unsigned short hstg[256];   // 512B [b][c] bf16

  // weights: compute waves only — 16 cols x 3 gates x K-quarter (96 VGPRs)
  bfrag wfrag[3][8];
  if (wave < 4) {
    #pragma unroll
    for (int g = 0; g < 3; ++g) {
      const float* wrow = whh + (size_t)(g * 1024 + jcol) * 1024 + wave * 256 + (lane >> 4) * 8;
      #pragma unroll
      for (int ks = 0; ks < 8; ++ks) {
        const float* p = wrow + ks * 32;
        f32x4 lo = *(const f32x4*)p;
        f32x4 hi = *(const f32x4*)(p + 4);
        bfrag f;
        f[0]=(short)f2bf(lo[0]); f[1]=(short)f2bf(lo[1]); f[2]=(short)f2bf(lo[2]); f[3]=(short)f2bf(lo[3]);
        f[4]=(short)f2bf(hi[0]); f[5]=(short)f2bf(hi[1]); f[6]=(short)f2bf(hi[2]); f[7]=(short)f2bf(hi[3]);
        wfrag[g][ks] = f;
      }
    }
  }
  float bih_r[3], bhh_r[3];
  #pragma unroll
  for (int g = 0; g < 3; ++g) {
    bih_r[g] = bihp[g * 1024 + jcol];
    bhh_r[g] = bhhp[g * 1024 + jcol];
  }

  float hprev[4][4] = {{0}}, hacc[4][4] = {{0}};
  const int xorm = (bl & 7) << 4;
  const char* lbase = (const char*)h_lds + bl * 2048;
  const int kb_st = (tid >> 2) * 32 + (tid & 3) * 8;   // staging byte-col (const/thread)

  ull   hv[2][16];        // ping-pong in-flight h (2 teams, 2 slots ahead)
  short gxr[2][4][3];     // ping-pong gx prefetch

  // prologue: teams 0 and 1 of step 0 (h(0)=0 from memset; superflags start 0)
  if (wave < 4) {
    #pragma unroll
    for (int p = 0; p < 2; ++p) {
      const ull* src = hbuf_q + p * 4096;   // parity 0
      #pragma unroll
      for (int j = 0; j < 16; ++j)
        hv[p][j] = __hip_atomic_load(src + j * 256 + tid, __ATOMIC_RELAXED,
                                     __HIP_MEMORY_SCOPE_AGENT);
    }
  }
  if (wave == 0) {
    #pragma unroll
    for (int p = 0; p < 2; ++p)
      #pragma unroll
      for (int r = 0; r < 4; ++r) {
        size_t base = ((size_t)(p * 16 + bsub + r) * SEQ + 0) * G3 + jcol;
        gxr[p][r][0] = gx[base];
        gxr[p][r][1] = gx[base + 1024];
        gxr[p][r][2] = gx[base + 2048];
      }
  }

  #pragma unroll 1
  for (int s = 0; s < SEQ; ++s) {
    #pragma unroll
    for (int t = 0; t < 4; ++t) {
      // ---- A: stage team t's h(s) from regs -> LDS (swizzled) ----
      if (wave < 4) {
        #pragma unroll
        for (int j = 0; j < 16; ++j)
          *(ull*)((char*)h_lds + j * 2048 + (kb_st ^ ((j & 7) << 4))) = hv[t & 1][j];
      }
      __syncthreads();   // S1

      // ---- C: partial gh over this wave's K-quarter (24 MFMAs) ----
      f32x4 a0 = {0.f,0.f,0.f,0.f}, a1 = {0.f,0.f,0.f,0.f}, a2 = {0.f,0.f,0.f,0.f};
      if (wave < 4) {
        #pragma unroll
        for (int ks = 0; ks < 8; ++ks) {
          int k2 = wave * 512 + ks * 64 + (lane >> 4) * 16;
          bfrag af = *(const bfrag*)(lbase + (k2 ^ xorm));
          a0 = __builtin_amdgcn_mfma_f32_16x16x32_bf16(af, wfrag[0][ks], a0, 0, 0, 0);
          a1 = __builtin_amdgcn_mfma_f32_16x16x32_bf16(af, wfrag[1][ks], a1, 0, 0, 0);
          a2 = __builtin_amdgcn_mfma_f32_16x16x32_bf16(af, wfrag[2][ks], a2, 0, 0, 0);
        }
        if (wave) {
          int w1 = wave - 1;
          *(f32x4*)&part[((0 * 3 + w1) * 64 + lane) * 4] = a0;
          *(f32x4*)&part[((1 * 3 + w1) * 64 + lane) * 4] = a1;
          *(f32x4*)&part[((2 * 3 + w1) * 64 + lane) * 4] = a2;
        }
      }
      __syncthreads();   // S2

      // ---- E: wave0 combine+gates; wave1 superflag poll for team 2-ahead ----
      if (wave == 0) {
        f32x4 s0 = a0, s1 = a1, s2 = a2;
        #pragma unroll
        for (int w1 = 0; w1 < 3; ++w1) {
          s0 += *(const f32x4*)&part[((0 * 3 + w1) * 64 + lane) * 4];
          s1 += *(const f32x4*)&part[((1 * 3 + w1) * 64 + lane) * 4];
          s2 += *(const f32x4*)&part[((2 * 3 + w1) * 64 + lane) * 4];
        }
        #pragma unroll
        for (int r = 0; r < 4; ++r) {
          float ghr = s0[r] + bhh_r[0];
          float ghz = s1[r] + bhh_r[1];
          float ghn = s2[r] + bhh_r[2];
          float rg = fsig(bf2f(gxr[t & 1][r][0]) + bih_r[0] + ghr);
          float zg = fsig(bf2f(gxr[t & 1][r][1]) + bih_r[1] + ghz);
          float ng = ftanh(bf2f(gxr[t & 1][r][2]) + bih_r[2] + rg * ghn);
          float hn = (1.f - zg) * ng + zg * hprev[t][r];
          hprev[t][r] = hn;
          hacc[t][r] += hn;
          hstg[(bsub + r) * 16 + bl] = f2bf(hn);
        }
      }
      if (wave == 1) {
        int u = (t + 2) & 3;
        unsigned tg = (unsigned)(s + ((t & 2) ? 1 : 0));
        while (__hip_atomic_load(superf + u * 16, __ATOMIC_RELAXED,
                                 __HIP_MEMORY_SCOPE_AGENT) < tg) { }
      }
      __syncthreads();   // S3

      // ---- G: compute waves issue 2-ahead loads; wave4 publishes+flags ----
      if (wave < 4) {
        int u  = (t + 2) & 3;
        int su = s + ((t & 2) ? 1 : 0);
        const ull* src = hbuf_q + (size_t)(su & 1) * 16384 + u * 4096;
        #pragma unroll
        for (int j = 0; j < 16; ++j)
          hv[t & 1][j] = __hip_atomic_load(src + j * 256 + tid, __ATOMIC_RELAXED,
                                           __HIP_MEMORY_SCOPE_AGENT);
        if (wave == 0) {
          int sg = (su < SEQ) ? su : (SEQ - 1);
          #pragma unroll
          for (int r = 0; r < 4; ++r) {
            size_t base = ((size_t)(u * 16 + bsub + r) * SEQ + sg) * G3 + jcol;
            gxr[t & 1][r][0] = gx[base];
            gxr[t & 1][r][1] = gx[base + 1024];
            gxr[t & 1][r][2] = gx[base + 2048];
          }
        }
      } else {
        // comms wave: publish team t's h(s+1) — one 8B store/lane, drain, flag
        ull v = ((const ull*)hstg)[lane];
        ull* dst = hbuf_q + (size_t)((s + 1) & 1) * 16384 + t * 4096
                 + (lane >> 2) * 256 + cg * 4 + (lane & 3);
        __hip_atomic_store(dst, v, __ATOMIC_RELAXED, __HIP_MEMORY_SCOPE_AGENT);
        asm volatile("s_waitcnt vmcnt(0)" ::: "memory");
        if (lane == 0)
          __hip_atomic_store(flags + t * 1024 + cg * 16, (unsigned)(s + 1),
                             __ATOMIC_RELAXED, __HIP_MEMORY_SCOPE_AGENT);
        // aggregation: WG cg<4 reduces team cg's 64 flags -> 1 superflag line
        if (cg < 4 && t == ((cg + 1) & 3)) {
          unsigned vt = (unsigned)((t > cg) ? (s + 1) : s);
          for (;;) {
            unsigned f = __hip_atomic_load(flags + cg * 1024 + lane * 16,
                                           __ATOMIC_RELAXED, __HIP_MEMORY_SCOPE_AGENT);
            if (__all((int)(f >= vt))) break;
          }
          if (lane == 0)
            __hip_atomic_store(superf + cg * 16, vt, __ATOMIC_RELAXED,
                               __HIP_MEMORY_SCOPE_AGENT);
        }
      }
    }
  }

  if (wave == 0) {
    #pragma unroll
    for (int t = 0; t < 4; ++t)
      #pragma unroll
      for (int r = 0; r < 4; ++r)
        hsum[(size_t)(t * 16 + bsub + r) * 1024 + jcol] = hacc[t][r] * (1.0f / 512.0f);
  }
}

// ---------- kernel 3: mean/logv projections (fp32) ----------
__global__ void proj_kernel(const float* __restrict__ hbar,
                            const float* __restrict__ wm, const float* __restrict__ bm,
                            const float* __restrict__ wl, const float* __restrict__ bl,
                            float* __restrict__ out)
{
  int b = blockIdx.x, t = threadIdx.x;  // 128 threads: 0-63 mean, 64-127 logv
  __shared__ float hrow[1024];
  for (int k = t; k < 1024; k += 128) hrow[k] = hbar[(size_t)b * 1024 + k];
  __syncthreads();
  int j = t & 63;
  const float* w = (t < 64) ? (wm + (size_t)j * 1024) : (wl + (size_t)j * 1024);
  float acc = (t < 64) ? bm[j] : bl[j];
  for (int k = 0; k < 1024; k += 4) {
    f32x4 wv = *(const f32x4*)(w + k);
    acc += hrow[k] * wv[0] + hrow[k+1] * wv[1] + hrow[k+2] * wv[2] + hrow[k+3] * wv[3];
  }
  out[(size_t)((t < 64) ? 0 : 4096) + b * 64 + j] = acc;
}

// ---------- launch ----------
extern "C" void kernel_launch(void* const* d_in, const int* in_sizes, int n_in,
                              void* d_out, int out_size, void* d_ws, size_t ws_size,
                              hipStream_t stream) {
  const int*   ids   = (const int*)d_in[0];
  const float* emb   = (const float*)d_in[1];
  const float* w_ih  = (const float*)d_in[2];
  const float* w_hh  = (const float*)d_in[3];
  const float* b_ih  = (const float*)d_in[4];
  const float* b_hh  = (const float*)d_in[5];
  const float* w_mean= (const float*)d_in[6];
  const float* b_mean= (const float*)d_in[7];
  const float* w_logv= (const float*)d_in[8];
  const float* b_logv= (const float*)d_in[9];
  float* out = (float*)d_out;

  char* ws = (char*)d_ws;
  // ws layout
  unsigned* superf = (unsigned*)(ws);                       //      1024 B (4 superflags, 64B apart)
  unsigned* flags  = (unsigned*)(ws + 1024);                //     16384 B (4 teams x 64 flags, 64B apart)
  ull* hbuf_q      = (ull*)(ws + 1024 + 16384);             //    262144 B [2][4][16][256] qwords bf16
  float* hsum      = (float*)(ws + 1024 + 16384 + 262144);  //    262144 B [64][1024] f32
  short* wihb      = (short*)(ws + 1024 + 16384 + 262144 + 262144);            //   3145728 B
  short* gxbuf     = (short*)(ws + 1024 + 16384 + 262144 + 262144 + 3145728);  // 201326592 B

  // zero superflags + flags + h double-buffers (deterministic across replays)
  hipMemsetAsync(ws, 0, 1024 + 16384 + 262144, stream);

  // 0: w_ih -> bf16
  cvt_wih_kernel<<<768, 256, 0, stream>>>(w_ih, wihb);
  // 1: gx GEMM
  gemm_gx_kernel<<<dim3(24, 256), 256, 0, stream>>>(ids, emb, wihb, gxbuf);
  // 2: persistent scan — 64 WGs x 320 thr (4 compute waves + 1 comms wave),
  //    4-team pipeline, superflag-gated exchange. 64 WGs co-resident.
  gru_scan_kernel<<<64, 320, 0, stream>>>(gxbuf, w_hh, b_ih, b_hh,
                                          hbuf_q, flags, superf, hsum);
  // 3: projections
  proj_kernel<<<64, 128, 0, stream>>>(hsum, w_mean, b_mean, w_logv, b_logv, out);
}

// Round 10
// 3195.147 us; speedup vs baseline: 2.8312x; 2.8312x over previous
//
#include <hip/hip_runtime.h>
#include <hip/hip_bf16.h>
#include <stdint.h>
#include <stddef.h>

// Problem sizes (fixed)
#define HID   1024
#define NB    64
#define SEQ   512
#define G3    3072   // 3*HID
#define EMB   512
#define LAT   64

typedef __attribute__((ext_vector_type(4))) float f32x4;
typedef __attribute__((ext_vector_type(8))) short bfrag;  // 8 bf16 (4 VGPRs)
typedef unsigned long long ull;

// ---------- helpers ----------
__device__ __forceinline__ unsigned short f2bf(float x) {   // RNE f32->bf16
  union { float f; unsigned u; } v; v.f = x;
  unsigned u = v.u + 0x7fffu + ((v.u >> 16) & 1u);
  return (unsigned short)(u >> 16);
}
__device__ __forceinline__ float bf2f(short s) {
  union { unsigned u; float f; } v; v.u = ((unsigned)(unsigned short)s) << 16;
  return v.f;
}
__device__ __forceinline__ float fsig(float x) {
  return 1.0f / (1.0f + __builtin_exp2f(-1.4426950408889634f * x));
}
__device__ __forceinline__ float ftanh(float x) {
  return 1.0f - 2.0f / (1.0f + __builtin_exp2f(2.8853900817779268f * x));
}
__device__ __forceinline__ void gload_lds16(const void* g, void* l) {
  __builtin_amdgcn_global_load_lds(
      (const __attribute__((address_space(1))) unsigned int*)g,
      (__attribute__((address_space(3))) unsigned int*)l, 16, 0, 0);
}

// ---------- kernel 0: w_ih f32 -> bf16 ----------
__global__ void cvt_wih_kernel(const float* __restrict__ in, short* __restrict__ out) {
  int i = (blockIdx.x * 256 + threadIdx.x) * 8;   // grid sized exactly
  f32x4 a = *(const f32x4*)(in + i);
  f32x4 b = *(const f32x4*)(in + i + 4);
  bfrag o;
  o[0]=(short)f2bf(a[0]); o[1]=(short)f2bf(a[1]); o[2]=(short)f2bf(a[2]); o[3]=(short)f2bf(a[3]);
  o[4]=(short)f2bf(b[0]); o[5]=(short)f2bf(b[1]); o[6]=(short)f2bf(b[2]); o[7]=(short)f2bf(b[3]);
  *(bfrag*)(out + i) = o;
}

// ---------- kernel 1: gx = emb[ids] @ w_ih^T  (bf16 MFMA, fp32 acc, bf16 out) ----------
__global__ void __launch_bounds__(256) gemm_gx_kernel(
    const int* __restrict__ ids, const float* __restrict__ emb,
    const short* __restrict__ wih, short* __restrict__ gx)
{
  const int nt = blockIdx.x, mt = blockIdx.y;
  const int tid = threadIdx.x;
  const int lane = tid & 63, wave = tid >> 6;
  const int wr = wave >> 1, wc = wave & 1;

  __shared__ __align__(16) short A_lds[128 * 48];
  __shared__ __align__(16) short B_lds[128 * 32];
  __shared__ int ids_s[128];

  if (tid < 128) ids_s[tid] = ids[mt * 128 + tid];
  __syncthreads();

  f32x4 acc[4][4];
  #pragma unroll
  for (int i = 0; i < 4; ++i)
    #pragma unroll
    for (int j = 0; j < 4; ++j) acc[i][j] = (f32x4){0.f, 0.f, 0.f, 0.f};

  const int r_stage = tid >> 1;
  const int kh = (tid & 1) * 16;

  #pragma unroll 1
  for (int kc = 0; kc < 16; ++kc) {
    __syncthreads();
    {
      const float* src = emb + (size_t)ids_s[r_stage] * 512 + kc * 32 + kh;
      f32x4 v0 = *(const f32x4*)(src);
      f32x4 v1 = *(const f32x4*)(src + 4);
      f32x4 v2 = *(const f32x4*)(src + 8);
      f32x4 v3 = *(const f32x4*)(src + 12);
      bfrag p0, p1;
      p0[0]=(short)f2bf(v0[0]); p0[1]=(short)f2bf(v0[1]); p0[2]=(short)f2bf(v0[2]); p0[3]=(short)f2bf(v0[3]);
      p0[4]=(short)f2bf(v1[0]); p0[5]=(short)f2bf(v1[1]); p0[6]=(short)f2bf(v1[2]); p0[7]=(short)f2bf(v1[3]);
      p1[0]=(short)f2bf(v2[0]); p1[1]=(short)f2bf(v2[1]); p1[2]=(short)f2bf(v2[2]); p1[3]=(short)f2bf(v2[3]);
      p1[4]=(short)f2bf(v3[0]); p1[5]=(short)f2bf(v3[1]); p1[6]=(short)f2bf(v3[2]); p1[7]=(short)f2bf(v3[3]);
      *(bfrag*)&A_lds[r_stage * 48 + kh]     = p0;
      *(bfrag*)&A_lds[r_stage * 48 + kh + 8] = p1;
    }
    {
      #pragma unroll
      for (int ii = 0; ii < 2; ++ii) {
        int i = wave * 2 + ii;
        const short* src = wih + (size_t)(nt * 128 + i * 16 + (lane >> 2)) * 512
                               + kc * 32 + (lane & 3) * 8;
        gload_lds16((const void*)src, (void*)&B_lds[i * 512]);
      }
    }
    asm volatile("s_waitcnt vmcnt(0)" ::: "memory");
    __syncthreads();

    bfrag a[4], b[4];
    #pragma unroll
    for (int mi = 0; mi < 4; ++mi)
      a[mi] = *(const bfrag*)&A_lds[(wr * 64 + mi * 16 + (lane & 15)) * 48 + (lane >> 4) * 8];
    #pragma unroll
    for (int ni = 0; ni < 4; ++ni)
      b[ni] = *(const bfrag*)&B_lds[(wc * 64 + ni * 16 + (lane & 15)) * 32 + (lane >> 4) * 8];
    #pragma unroll
    for (int mi = 0; mi < 4; ++mi)
      #pragma unroll
      for (int ni = 0; ni < 4; ++ni)
        acc[mi][ni] = __builtin_amdgcn_mfma_f32_16x16x32_bf16(a[mi], b[ni], acc[mi][ni], 0, 0, 0);
  }

  #pragma unroll
  for (int mi = 0; mi < 4; ++mi)
    #pragma unroll
    for (int ni = 0; ni < 4; ++ni)
      #pragma unroll
      for (int r = 0; r < 4; ++r) {
        int m = mt * 128 + wr * 64 + mi * 16 + (lane >> 4) * 4 + r;
        int n = nt * 128 + wc * 64 + ni * 16 + (lane & 15);
        gx[(size_t)m * G3 + n] = (short)f2bf(acc[mi][ni][r]);
      }
}

// ---------- kernel 2: persistent GRU scan — 2-team pipelined (round-7 body) ----------
// 128 WGs x 256 thr (4 waves = K-quarters, EXACT round-7 compute body; VGPR ~200).
// WG = (pair = bid>>6 -> teams {2p,2p+1}, cg = bid&63 -> 16 cols, SAME wfrag for
// both teams). Per step: slot0 computes team A, slot1 team B. Team X's sync chain
// (publish+drain+flag / poll / load) overlaps the other team's compute slot:
// wave1 polls pre-S1 (flag ~1 slot old), h loads issue post-S1 (1 slot to land).
// Protocol audit: polls wait only on strictly-earlier (step,slot) publishes
// (acyclic); h(s+2) write is flag-gated behind all WGs having staged h(s) (WAR).
__global__ void __launch_bounds__(256, 1) gru_scan_kernel(
    const short* __restrict__ gx, const float* __restrict__ whh,
    const float* __restrict__ bihp, const float* __restrict__ bhhp,
    ull* __restrict__ hbuf_q, unsigned* __restrict__ flags,
    float* __restrict__ hsum)
{
  const int cg   = blockIdx.x & 63;        // col-group
  const int pair = blockIdx.x >> 6;        // 0..1
  const int tA   = pair * 2, tB = tA + 1;  // this WG's two teams
  const int tid  = threadIdx.x;
  const int lane = tid & 63, wave = tid >> 6;   // wave = K-quarter 0..3
  const int bl   = lane & 15;
  const int bsub = (lane >> 4) * 4;
  const int jcol = cg * 16 + bl;

  __shared__ __align__(16) short h_lds[16 * 1024];    // 32KB [b][k] swizzled
  __shared__ __align__(16) float part[3 * 3 * 256];   // 9KB  [g][wave-1][lane*4]
  __shared__ __align__(16) unsigned short hstg[256];  // 512B [b][c] bf16

  // --- weights: 16 cols x 3 gates x K-quarter (96 VGPRs), shared by both teams ---
  bfrag wfrag[3][8];
  #pragma unroll
  for (int g = 0; g < 3; ++g) {
    const float* wrow = whh + (size_t)(g * 1024 + jcol) * 1024 + wave * 256 + (lane >> 4) * 8;
    #pragma unroll
    for (int ks = 0; ks < 8; ++ks) {
      const float* p = wrow + ks * 32;
      f32x4 lo = *(const f32x4*)p;
      f32x4 hi = *(const f32x4*)(p + 4);
      bfrag f;
      f[0]=(short)f2bf(lo[0]); f[1]=(short)f2bf(lo[1]); f[2]=(short)f2bf(lo[2]); f[3]=(short)f2bf(lo[3]);
      f[4]=(short)f2bf(hi[0]); f[5]=(short)f2bf(hi[1]); f[6]=(short)f2bf(hi[2]); f[7]=(short)f2bf(hi[3]);
      wfrag[g][ks] = f;
    }
  }
  float bih_r[3], bhh_r[3];
  #pragma unroll
  for (int g = 0; g < 3; ++g) {
    bih_r[g] = bihp[g * 1024 + jcol];
    bhh_r[g] = bhhp[g * 1024 + jcol];
  }

  float hprevA[4] = {0,0,0,0}, haccA[4] = {0,0,0,0};
  float hprevB[4] = {0,0,0,0}, haccB[4] = {0,0,0,0};
  const int xorm = (bl & 7) << 4;
  const char* lbase = (const char*)h_lds + bl * 2048;
  unsigned* flagsA = flags + tA * 1024;   // 64 flags, 64B apart (index cg*16)
  unsigned* flagsB = flags + tB * 1024;

  ull   hv[16];            // single in-flight h buffer (reused every slot)
  short gxrA[4][3], gxrB[4][3];

  // ---- one slot: stage hv->LDS, poll(next team), S1, issue next loads,
  //      MFMA, S2, combine+gates, S3, publish+flag / gx prefetch ----
#define GRU_SLOT(HPREV, HACC, GXR, POLL_FLAGS, POLL_TGT, LOAD_SRC,              \
                 PUB_DST, MY_FLAG, PUB_VAL, GX_ROWB, GX_SNEXT)                  \
  {                                                                             \
    /* A: stage hv (current team's h) -> LDS, swizzled */                       \
    _Pragma("unroll")                                                           \
    for (int j = 0; j < 16; ++j) {                                              \
      int q = j * 256 + tid;                                                    \
      int cgq = q >> 6, b = (q >> 2) & 15, c4 = q & 3;                          \
      *(ull*)((char*)h_lds + b * 2048 +                                         \
              ((cgq * 32 + c4 * 8) ^ ((b & 7) << 4))) = hv[j];                  \
    }                                                                           \
    if (wave == 1) {  /* poll next team's flags (set ~1 slot ago) */            \
      for (;;) {                                                                \
        unsigned v = __hip_atomic_load((POLL_FLAGS) + lane * 16,                \
                                       __ATOMIC_RELAXED, __HIP_MEMORY_SCOPE_AGENT); \
        if (__all((int)(v >= (unsigned)(POLL_TGT)))) break;                     \
      }                                                                         \
    }                                                                           \
    __syncthreads();  /* S1 */                                                  \
    /* issue next team's h loads (gated by poll via S1); 1 slot to land */      \
    _Pragma("unroll")                                                           \
    for (int j = 0; j < 16; ++j)                                                \
      hv[j] = __hip_atomic_load((LOAD_SRC) + j * 256 + tid,                     \
                                __ATOMIC_RELAXED, __HIP_MEMORY_SCOPE_AGENT);    \
    /* B: partial gh over this wave's K-quarter (24 MFMAs) */                   \
    f32x4 a0 = {0.f,0.f,0.f,0.f}, a1 = {0.f,0.f,0.f,0.f}, a2 = {0.f,0.f,0.f,0.f}; \
    _Pragma("unroll")                                                           \
    for (int ks = 0; ks < 8; ++ks) {                                            \
      int k2 = wave * 512 + ks * 64 + (lane >> 4) * 16;                         \
      bfrag af = *(const bfrag*)(lbase + (k2 ^ xorm));                          \
      a0 = __builtin_amdgcn_mfma_f32_16x16x32_bf16(af, wfrag[0][ks], a0, 0, 0, 0); \
      a1 = __builtin_amdgcn_mfma_f32_16x16x32_bf16(af, wfrag[1][ks], a1, 0, 0, 0); \
      a2 = __builtin_amdgcn_mfma_f32_16x16x32_bf16(af, wfrag[2][ks], a2, 0, 0, 0); \
    }                                                                           \
    if (wave) {                                                                 \
      int w1 = wave - 1;                                                        \
      *(f32x4*)&part[((0 * 3 + w1) * 64 + lane) * 4] = a0;                      \
      *(f32x4*)&part[((1 * 3 + w1) * 64 + lane) * 4] = a1;                      \
      *(f32x4*)&part[((2 * 3 + w1) * 64 + lane) * 4] = a2;                      \
    }                                                                           \
    __syncthreads();  /* S2 */                                                  \
    if (wave == 0) {  /* combine + gates (fp32) + stage h_new */                \
      f32x4 s0 = a0, s1 = a1, s2 = a2;                                          \
      _Pragma("unroll")                                                         \
      for (int w1 = 0; w1 < 3; ++w1) {                                          \
        s0 += *(const f32x4*)&part[((0 * 3 + w1) * 64 + lane) * 4];             \
        s1 += *(const f32x4*)&part[((1 * 3 + w1) * 64 + lane) * 4];             \
        s2 += *(const f32x4*)&part[((2 * 3 + w1) * 64 + lane) * 4];             \
      }                                                                         \
      _Pragma("unroll")                                                         \
      for (int r = 0; r < 4; ++r) {                                             \
        float ghr = s0[r] + bhh_r[0];                                           \
        float ghz = s1[r] + bhh_r[1];                                           \
        float ghn = s2[r] + bhh_r[2];                                           \
        float rg = fsig(bf2f((GXR)[r][0]) + bih_r[0] + ghr);                    \
        float zg = fsig(bf2f((GXR)[r][1]) + bih_r[1] + ghz);                    \
        float ng = ftanh(bf2f((GXR)[r][2]) + bih_r[2] + rg * ghn);              \
        float hn = (1.f - zg) * ng + zg * (HPREV)[r];                           \
        (HPREV)[r] = hn;                                                        \
        (HACC)[r] += hn;                                                        \
        hstg[(bsub + r) * 16 + bl] = f2bf(hn);                                  \
      }                                                                         \
    }                                                                           \
    __syncthreads();  /* S3 */                                                  \
    if (wave == 1) {  /* publish 512B burst + drain + flag (off compute path) */\
      ull v = ((const ull*)hstg)[lane];                                         \
      __hip_atomic_store((PUB_DST) + cg * 64 + lane, v,                         \
                         __ATOMIC_RELAXED, __HIP_MEMORY_SCOPE_AGENT);           \
      asm volatile("s_waitcnt vmcnt(0)" ::: "memory");                          \
      if (lane == 0)                                                            \
        __hip_atomic_store((MY_FLAG), (unsigned)(PUB_VAL),                      \
                           __ATOMIC_RELAXED, __HIP_MEMORY_SCOPE_AGENT);         \
    }                                                                           \
    if (wave == 0) {  /* prefetch this team's gx for its next step */           \
      _Pragma("unroll")                                                         \
      for (int r = 0; r < 4; ++r) {                                             \
        size_t base = ((size_t)((GX_ROWB) + bsub + r) * SEQ + (GX_SNEXT)) * G3 + jcol; \
        (GXR)[r][0] = gx[base];                                                 \
        (GXR)[r][1] = gx[base + 1024];                                          \
        (GXR)[r][2] = gx[base + 2048];                                          \
      }                                                                         \
    }                                                                           \
  }

  // prologue: team A h(0) (parity 0, zeros from memset); gx step 0 both teams
  {
    const ull* src = hbuf_q + tA * 4096;
    #pragma unroll
    for (int j = 0; j < 16; ++j)
      hv[j] = __hip_atomic_load(src + j * 256 + tid, __ATOMIC_RELAXED,
                                __HIP_MEMORY_SCOPE_AGENT);
  }
  if (wave == 0) {
    #pragma unroll
    for (int r = 0; r < 4; ++r) {
      size_t ba = ((size_t)(tA * 16 + bsub + r) * SEQ) * G3 + jcol;
      size_t bb = ((size_t)(tB * 16 + bsub + r) * SEQ) * G3 + jcol;
      gxrA[r][0] = gx[ba]; gxrA[r][1] = gx[ba + 1024]; gxrA[r][2] = gx[ba + 2048];
      gxrB[r][0] = gx[bb]; gxrB[r][1] = gx[bb + 1024]; gxrB[r][2] = gx[bb + 2048];
    }
  }

  #pragma unroll 1
  for (int s = 0; s < SEQ; ++s) {
    int sn = (s + 1 < SEQ) ? (s + 1) : s;
    // ---- slot 0: team A (h_A(s) -> h_A(s+1)); load h_B(s); poll flags_B >= s
    GRU_SLOT(hprevA, haccA, gxrA,
             flagsB, s,
             hbuf_q + (size_t)(s & 1) * 16384 + tB * 4096,
             hbuf_q + (size_t)((s + 1) & 1) * 16384 + tA * 4096,
             flagsA + cg * 16, s + 1,
             tA * 16, sn)
    // ---- slot 1: team B (h_B(s) -> h_B(s+1)); load h_A(s+1); poll flags_A >= s+1
    GRU_SLOT(hprevB, haccB, gxrB,
             flagsA, s + 1,
             hbuf_q + (size_t)((s + 1) & 1) * 16384 + tA * 4096,
             hbuf_q + (size_t)((s + 1) & 1) * 16384 + tB * 4096,
             flagsB + cg * 16, s + 1,
             tB * 16, sn)
  }
#undef GRU_SLOT

  if (wave == 0) {
    #pragma unroll
    for (int r = 0; r < 4; ++r) {
      hsum[(size_t)(tA * 16 + bsub + r) * 1024 + jcol] = haccA[r] * (1.0f / 512.0f);
      hsum[(size_t)(tB * 16 + bsub + r) * 1024 + jcol] = haccB[r] * (1.0f / 512.0f);
    }
  }
}

// ---------- kernel 3: mean/logv projections (fp32) ----------
__global__ void proj_kernel(const float* __restrict__ hbar,
                            const float* __restrict__ wm, const float* __restrict__ bm,
                            const float* __restrict__ wl, const float* __restrict__ bl,
                            float* __restrict__ out)
{
  int b = blockIdx.x, t = threadIdx.x;  // 128 threads: 0-63 mean, 64-127 logv
  __shared__ float hrow[1024];
  for (int k = t; k < 1024; k += 128) hrow[k] = hbar[(size_t)b * 1024 + k];
  __syncthreads();
  int j = t & 63;
  const float* w = (t < 64) ? (wm + (size_t)j * 1024) : (wl + (size_t)j * 1024);
  float acc = (t < 64) ? bm[j] : bl[j];
  for (int k = 0; k < 1024; k += 4) {
    f32x4 wv = *(const f32x4*)(w + k);
    acc += hrow[k] * wv[0] + hrow[k+1] * wv[1] + hrow[k+2] * wv[2] + hrow[k+3] * wv[3];
  }
  out[(size_t)((t < 64) ? 0 : 4096) + b * 64 + j] = acc;
}

// ---------- launch ----------
extern "C" void kernel_launch(void* const* d_in, const int* in_sizes, int n_in,
                              void* d_out, int out_size, void* d_ws, size_t ws_size,
                              hipStream_t stream) {
  const int*   ids   = (const int*)d_in[0];
  const float* emb   = (const float*)d_in[1];
  const float* w_ih  = (const float*)d_in[2];
  const float* w_hh  = (const float*)d_in[3];
  const float* b_ih  = (const float*)d_in[4];
  const float* b_hh  = (const float*)d_in[5];
  const float* w_mean= (const float*)d_in[6];
  const float* b_mean= (const float*)d_in[7];
  const float* w_logv= (const float*)d_in[8];
  const float* b_logv= (const float*)d_in[9];
  float* out = (float*)d_out;

  char* ws = (char*)d_ws;
  // ws layout
  unsigned* flags = (unsigned*)(ws);                   //     16384 B (4 teams x 64 flags, 64B apart)
  ull* hbuf_q     = (ull*)(ws + 16384);                //    262144 B [2][4][4096] qwords bf16 ([cg][b][c4])
  float* hsum     = (float*)(ws + 16384 + 262144);     //    262144 B [64][1024] f32
  short* wihb     = (short*)(ws + 16384 + 262144 + 262144);            //   3145728 B
  short* gxbuf    = (short*)(ws + 16384 + 262144 + 262144 + 3145728);  // 201326592 B

  // zero flags + h double-buffers (deterministic across graph replays)
  hipMemsetAsync(ws, 0, 16384 + 262144, stream);

  // 0: w_ih -> bf16
  cvt_wih_kernel<<<768, 256, 0, stream>>>(w_ih, wihb);
  // 1: gx GEMM
  gemm_gx_kernel<<<dim3(24, 256), 256, 0, stream>>>(ids, emb, wihb, gxbuf);
  // 2: persistent scan — 128 WGs x 256 thr (round-7 wave shape, ~200 VGPR),
  //    2-team pipeline per WG; co-residency trivial (128 <= 256 CUs).
  gru_scan_kernel<<<128, 256, 0, stream>>>(gxbuf, w_hh, b_ih, b_hh,
                                           hbuf_q, flags, hsum);
  // 3: projections
  proj_kernel<<<64, 128, 0, stream>>>(hsum, w_mean, b_mean, w_logv, b_logv, out);
}

// Round 11
// 2696.553 us; speedup vs baseline: 3.3547x; 1.1849x over previous
//
#include <hip/hip_runtime.h>
#include <hip/hip_bf16.h>
#include <stdint.h>
#include <stddef.h>

// Problem sizes (fixed)
#define HID   1024
#define NB    64
#define SEQ   512
#define G3    3072   // 3*HID
#define EMB   512
#define LAT   64

typedef __attribute__((ext_vector_type(4))) float f32x4;
typedef __attribute__((ext_vector_type(8))) short bfrag;  // 8 bf16 (4 VGPRs)
typedef unsigned long long ull;

// ---------- helpers ----------
__device__ __forceinline__ unsigned short f2bf(float x) {   // RNE f32->bf16
  union { float f; unsigned u; } v; v.f = x;
  unsigned u = v.u + 0x7fffu + ((v.u >> 16) & 1u);
  return (unsigned short)(u >> 16);
}
__device__ __forceinline__ float bf2f(short s) {
  union { unsigned u; float f; } v; v.u = ((unsigned)(unsigned short)s) << 16;
  return v.f;
}
__device__ __forceinline__ float fsig(float x) {
  return 1.0f / (1.0f + __builtin_exp2f(-1.4426950408889634f * x));
}
__device__ __forceinline__ float ftanh(float x) {
  return 1.0f - 2.0f / (1.0f + __builtin_exp2f(2.8853900817779268f * x));
}
__device__ __forceinline__ void gload_lds16(const void* g, void* l) {
  __builtin_amdgcn_global_load_lds(
      (const __attribute__((address_space(1))) unsigned int*)g,
      (__attribute__((address_space(3))) unsigned int*)l, 16, 0, 0);
}

// ---------- kernel 0: w_ih f32 -> bf16 ----------
__global__ void cvt_wih_kernel(const float* __restrict__ in, short* __restrict__ out) {
  int i = (blockIdx.x * 256 + threadIdx.x) * 8;   // grid sized exactly
  f32x4 a = *(const f32x4*)(in + i);
  f32x4 b = *(const f32x4*)(in + i + 4);
  bfrag o;
  o[0]=(short)f2bf(a[0]); o[1]=(short)f2bf(a[1]); o[2]=(short)f2bf(a[2]); o[3]=(short)f2bf(a[3]);
  o[4]=(short)f2bf(b[0]); o[5]=(short)f2bf(b[1]); o[6]=(short)f2bf(b[2]); o[7]=(short)f2bf(b[3]);
  *(bfrag*)(out + i) = o;
}

// ---------- kernel 1: gx = emb[ids] @ w_ih^T  (bf16 MFMA, fp32 acc, bf16 out) ----------
__global__ void __launch_bounds__(256) gemm_gx_kernel(
    const int* __restrict__ ids, const float* __restrict__ emb,
    const short* __restrict__ wih, short* __restrict__ gx)
{
  const int nt = blockIdx.x, mt = blockIdx.y;
  const int tid = threadIdx.x;
  const int lane = tid & 63, wave = tid >> 6;
  const int wr = wave >> 1, wc = wave & 1;

  __shared__ __align__(16) short A_lds[128 * 48];
  __shared__ __align__(16) short B_lds[128 * 32];
  __shared__ int ids_s[128];

  if (tid < 128) ids_s[tid] = ids[mt * 128 + tid];
  __syncthreads();

  f32x4 acc[4][4];
  #pragma unroll
  for (int i = 0; i < 4; ++i)
    #pragma unroll
    for (int j = 0; j < 4; ++j) acc[i][j] = (f32x4){0.f, 0.f, 0.f, 0.f};

  const int r_stage = tid >> 1;
  const int kh = (tid & 1) * 16;

  #pragma unroll 1
  for (int kc = 0; kc < 16; ++kc) {
    __syncthreads();
    {
      const float* src = emb + (size_t)ids_s[r_stage] * 512 + kc * 32 + kh;
      f32x4 v0 = *(const f32x4*)(src);
      f32x4 v1 = *(const f32x4*)(src + 4);
      f32x4 v2 = *(const f32x4*)(src + 8);
      f32x4 v3 = *(const f32x4*)(src + 12);
      bfrag p0, p1;
      p0[0]=(short)f2bf(v0[0]); p0[1]=(short)f2bf(v0[1]); p0[2]=(short)f2bf(v0[2]); p0[3]=(short)f2bf(v0[3]);
      p0[4]=(short)f2bf(v1[0]); p0[5]=(short)f2bf(v1[1]); p0[6]=(short)f2bf(v1[2]); p0[7]=(short)f2bf(v1[3]);
      p1[0]=(short)f2bf(v2[0]); p1[1]=(short)f2bf(v2[1]); p1[2]=(short)f2bf(v2[2]); p1[3]=(short)f2bf(v2[3]);
      p1[4]=(short)f2bf(v3[0]); p1[5]=(short)f2bf(v3[1]); p1[6]=(short)f2bf(v3[2]); p1[7]=(short)f2bf(v3[3]);
      *(bfrag*)&A_lds[r_stage * 48 + kh]     = p0;
      *(bfrag*)&A_lds[r_stage * 48 + kh + 8] = p1;
    }
    {
      #pragma unroll
      for (int ii = 0; ii < 2; ++ii) {
        int i = wave * 2 + ii;
        const short* src = wih + (size_t)(nt * 128 + i * 16 + (lane >> 2)) * 512
                               + kc * 32 + (lane & 3) * 8;
        gload_lds16((const void*)src, (void*)&B_lds[i * 512]);
      }
    }
    asm volatile("s_waitcnt vmcnt(0)" ::: "memory");
    __syncthreads();

    bfrag a[4], b[4];
    #pragma unroll
    for (int mi = 0; mi < 4; ++mi)
      a[mi] = *(const bfrag*)&A_lds[(wr * 64 + mi * 16 + (lane & 15)) * 48 + (lane >> 4) * 8];
    #pragma unroll
    for (int ni = 0; ni < 4; ++ni)
      b[ni] = *(const bfrag*)&B_lds[(wc * 64 + ni * 16 + (lane & 15)) * 32 + (lane >> 4) * 8];
    #pragma unroll
    for (int mi = 0; mi < 4; ++mi)
      #pragma unroll
      for (int ni = 0; ni < 4; ++ni)
        acc[mi][ni] = __builtin_amdgcn_mfma_f32_16x16x32_bf16(a[mi], b[ni], acc[mi][ni], 0, 0, 0);
  }

  #pragma unroll
  for (int mi = 0; mi < 4; ++mi)
    #pragma unroll
    for (int ni = 0; ni < 4; ++ni)
      #pragma unroll
      for (int r = 0; r < 4; ++r) {
        int m = mt * 128 + wr * 64 + mi * 16 + (lane >> 4) * 4 + r;
        int n = nt * 128 + wc * 64 + ni * 16 + (lane & 15);
        gx[(size_t)m * G3 + n] = (short)f2bf(acc[mi][ni][r]);
      }
}

// ---------- kernel 2: persistent GRU scan (round-7 structure + 2 counter-targeted fixes) ----------
// 256 WGs x 256 thr (4 waves). WG = (team = bid>>6 owns 16 batch rows,
// cg = bid&63 owns 16 hidden cols). Wave = K-quarter (wfrag[3][8] = 96 VGPRs).
// FIX A (poll congestion): flags packed 4B apart -> one wave poll touches 4 IF
//   lines instead of 64.
// FIX B (LDS conflicts): part[] exchange component-split (lane stride 4B,
//   2-way = free) instead of f32x4 16B stride (8-way conflict).
__global__ void __launch_bounds__(256, 1) gru_scan_kernel(
    const short* __restrict__ gx, const float* __restrict__ whh,
    const float* __restrict__ bihp, const float* __restrict__ bhhp,
    ull* __restrict__ hbuf_q, unsigned int* __restrict__ flags,
    float* __restrict__ hsum)
{
  const int wg   = blockIdx.x;       // 0..255
  const int team = wg >> 6;          // 0..3
  const int cg   = wg & 63;          // col-group
  const int tid  = threadIdx.x;
  const int lane = tid & 63, wave = tid >> 6;   // wave = K-quarter 0..3
  const int bl   = lane & 15;
  const int bsub = (lane >> 4) * 4;
  const int jcol = cg * 16 + bl;
  const int bteam = team * 16;

  __shared__ __align__(16) short h_lds[16 * 1024];   // 32 KB [b][k] swizzled
  __shared__ __align__(16) float part[9 * 4 * 64];   // 9 KB: [row(g,w1)][comp][lane]
  __shared__ __align__(16) short hstg[256];          // 512 B [b][c] exchange order

  // --- weights: 16 cols x 3 gates x K-quarter as B-frags (bf16), 96 VGPRs ---
  bfrag wfrag[3][8];
  #pragma unroll
  for (int g = 0; g < 3; ++g) {
    const float* wrow = whh + (size_t)(g * 1024 + jcol) * 1024 + wave * 256 + (lane >> 4) * 8;
    #pragma unroll
    for (int ks = 0; ks < 8; ++ks) {
      const float* p = wrow + ks * 32;
      f32x4 lo = *(const f32x4*)p;
      f32x4 hi = *(const f32x4*)(p + 4);
      bfrag f;
      f[0]=(short)f2bf(lo[0]); f[1]=(short)f2bf(lo[1]); f[2]=(short)f2bf(lo[2]); f[3]=(short)f2bf(lo[3]);
      f[4]=(short)f2bf(hi[0]); f[5]=(short)f2bf(hi[1]); f[6]=(short)f2bf(hi[2]); f[7]=(short)f2bf(hi[3]);
      wfrag[g][ks] = f;
    }
  }
  float bih_r[3], bhh_r[3];
  #pragma unroll
  for (int g = 0; g < 3; ++g) {
    bih_r[g] = bihp[g * 1024 + jcol];
    bhh_r[g] = bhhp[g * 1024 + jcol];
  }

  float hprev[4] = {0.f, 0.f, 0.f, 0.f};
  float hacc[4]  = {0.f, 0.f, 0.f, 0.f};
  const int xorm = (bl & 7) << 4;
  const char* lbase = (const char*)h_lds + bl * 2048;
  unsigned int* fteam  = flags + team * 64;    // FIX A: 64 contiguous u32 (256B)
  unsigned int* myflag = fteam + cg;

  // gx prefetch for current step (wave 0 = combiner)
  short gxr_[4][3];
  if (wave == 0) {
    #pragma unroll
    for (int r = 0; r < 4; ++r) {
      size_t base = ((size_t)(bteam + bsub + r) * SEQ + 0) * G3 + jcol;
      gxr_[r][0] = gx[base];
      gxr_[r][1] = gx[base + 1024];
      gxr_[r][2] = gx[base + 2048];
    }
  }

  #pragma unroll 1
  for (int s = 0; s < SEQ; ++s) {
    const ull* hsrc = hbuf_q + ((s & 1) ? 16384 : 0) + team * 4096;       // 4096 qwords
    ull*       hdst = hbuf_q + (((s + 1) & 1) ? 16384 : 0) + team * 4096;

    // 1. stage team h(s) -> LDS: coalesced agent 8B loads (512B/wave-instr),
    //    exchange layout [cg][b][c4] -> LDS [b][k] with the XOR swizzle.
    {
      ull hv[16];
      #pragma unroll
      for (int j = 0; j < 16; ++j)
        hv[j] = __hip_atomic_load(hsrc + j * 256 + tid, __ATOMIC_RELAXED,
                                  __HIP_MEMORY_SCOPE_AGENT);
      #pragma unroll
      for (int j = 0; j < 16; ++j) {
        int q  = j * 256 + tid;
        int cgq = q >> 6, b = (q >> 2) & 15, cq = q & 3;
        *(ull*)((char*)h_lds + b * 2048 + ((cgq * 32 + cq * 8) ^ ((b & 7) << 4))) = hv[j];
      }
    }
    __syncthreads();   // S1

    // 2. partial gh over this wave's K-quarter: 24 MFMAs
    f32x4 a0 = {0.f,0.f,0.f,0.f}, a1 = {0.f,0.f,0.f,0.f}, a2 = {0.f,0.f,0.f,0.f};
    #pragma unroll
    for (int ks = 0; ks < 8; ++ks) {
      int k2 = wave * 512 + ks * 64 + (lane >> 4) * 16;   // byte offset of k*2
      bfrag af = *(const bfrag*)(lbase + (k2 ^ xorm));
      a0 = __builtin_amdgcn_mfma_f32_16x16x32_bf16(af, wfrag[0][ks], a0, 0, 0, 0);
      a1 = __builtin_amdgcn_mfma_f32_16x16x32_bf16(af, wfrag[1][ks], a1, 0, 0, 0);
      a2 = __builtin_amdgcn_mfma_f32_16x16x32_bf16(af, wfrag[2][ks], a2, 0, 0, 0);
    }
    if (wave) {
      // FIX B: component-split scalar stores, lane stride 4B (2-way = free)
      int w1 = wave - 1;
      #pragma unroll
      for (int c = 0; c < 4; ++c) {
        part[((0 * 3 + w1) * 4 + c) * 64 + lane] = a0[c];
        part[((1 * 3 + w1) * 4 + c) * 64 + lane] = a1[c];
        part[((2 * 3 + w1) * 4 + c) * 64 + lane] = a2[c];
      }
    }
    __syncthreads();   // S2

    // 3. wave 0: combine K-quarters, gates (fp32), stage h_new in LDS
    if (wave == 0) {
      f32x4 s0 = a0, s1 = a1, s2 = a2;
      #pragma unroll
      for (int w1 = 0; w1 < 3; ++w1)
        #pragma unroll
        for (int c = 0; c < 4; ++c) {
          s0[c] += part[((0 * 3 + w1) * 4 + c) * 64 + lane];
          s1[c] += part[((1 * 3 + w1) * 4 + c) * 64 + lane];
          s2[c] += part[((2 * 3 + w1) * 4 + c) * 64 + lane];
        }
      #pragma unroll
      for (int r = 0; r < 4; ++r) {
        float ghr = s0[r] + bhh_r[0];
        float ghz = s1[r] + bhh_r[1];
        float ghn = s2[r] + bhh_r[2];
        float rg = fsig(bf2f(gxr_[r][0]) + bih_r[0] + ghr);
        float zg = fsig(bf2f(gxr_[r][1]) + bih_r[1] + ghz);
        float ng = ftanh(bf2f(gxr_[r][2]) + bih_r[2] + rg * ghn);
        float hn = (1.f - zg) * ng + zg * hprev[r];
        hprev[r] = hn;
        hacc[r] += hn;
        hstg[(bsub + r) * 16 + bl] = (short)f2bf(hn);   // exchange order [b][c]
      }
    }
    __syncthreads();   // S3

    // 4. wave 1: ONE contiguous 512B agent burst + drain + flag.
    //    wave 0: prefetch next gx, then poll the team's packed 64-flag line.
    if (wave == 1) {
      ull v = ((const ull*)hstg)[lane];
      __hip_atomic_store(hdst + cg * 64 + lane, v, __ATOMIC_RELAXED,
                         __HIP_MEMORY_SCOPE_AGENT);
      asm volatile("s_waitcnt vmcnt(0)" ::: "memory");   // this wave's stores done
      if (lane == 0)
        __hip_atomic_store(myflag, (unsigned)(s + 1), __ATOMIC_RELAXED,
                           __HIP_MEMORY_SCOPE_AGENT);
    }
    if (wave == 0) {
      int sn = (s + 1 < SEQ) ? (s + 1) : s;
      #pragma unroll
      for (int r = 0; r < 4; ++r) {
        size_t base = ((size_t)(bteam + bsub + r) * SEQ + sn) * G3 + jcol;
        gxr_[r][0] = gx[base];
        gxr_[r][1] = gx[base + 1024];
        gxr_[r][2] = gx[base + 2048];
      }
      unsigned tgt = (unsigned)(s + 1);
      for (;;) {     // FIX A: 64 lanes load 64 contiguous u32 = 4 IF lines
        unsigned v = __hip_atomic_load(fteam + lane, __ATOMIC_RELAXED,
                                       __HIP_MEMORY_SCOPE_AGENT);
        if (__all((int)(v >= tgt))) break;
      }
    }
    __syncthreads();   // S4
  }

  if (wave == 0) {
    #pragma unroll
    for (int r = 0; r < 4; ++r)
      hsum[(size_t)(bteam + bsub + r) * 1024 + jcol] = hacc[r] * (1.0f / 512.0f);
  }
}

// ---------- kernel 3: mean/logv projections (fp32) ----------
__global__ void proj_kernel(const float* __restrict__ hbar,
                            const float* __restrict__ wm, const float* __restrict__ bm,
                            const float* __restrict__ wl, const float* __restrict__ bl,
                            float* __restrict__ out)
{
  int b = blockIdx.x, t = threadIdx.x;  // 128 threads: 0-63 mean, 64-127 logv
  __shared__ float hrow[1024];
  for (int k = t; k < 1024; k += 128) hrow[k] = hbar[(size_t)b * 1024 + k];
  __syncthreads();
  int j = t & 63;
  const float* w = (t < 64) ? (wm + (size_t)j * 1024) : (wl + (size_t)j * 1024);
  float acc = (t < 64) ? bm[j] : bl[j];
  for (int k = 0; k < 1024; k += 4) {
    f32x4 wv = *(const f32x4*)(w + k);
    acc += hrow[k] * wv[0] + hrow[k+1] * wv[1] + hrow[k+2] * wv[2] + hrow[k+3] * wv[3];
  }
  out[(size_t)((t < 64) ? 0 : 4096) + b * 64 + j] = acc;
}

// ---------- launch ----------
extern "C" void kernel_launch(void* const* d_in, const int* in_sizes, int n_in,
                              void* d_out, int out_size, void* d_ws, size_t ws_size,
                              hipStream_t stream) {
  const int*   ids   = (const int*)d_in[0];
  const float* emb   = (const float*)d_in[1];
  const float* w_ih  = (const float*)d_in[2];
  const float* w_hh  = (const float*)d_in[3];
  const float* b_ih  = (const float*)d_in[4];
  const float* b_hh  = (const float*)d_in[5];
  const float* w_mean= (const float*)d_in[6];
  const float* b_mean= (const float*)d_in[7];
  const float* w_logv= (const float*)d_in[8];
  const float* b_logv= (const float*)d_in[9];
  float* out = (float*)d_out;

  char* ws = (char*)d_ws;
  // ws layout
  unsigned int* flags = (unsigned int*)(ws);                 //      4096 B (4 teams x 64 packed u32)
  ull* hbuf_q        = (ull*)(ws + 4096);                    //    262144 B [2][4][4096] qwords bf16 ([cg][b][c4])
  float* hsum        = (float*)(ws + 4096 + 262144);         //    262144 B [64][1024] f32
  short* wihb        = (short*)(ws + 4096 + 262144 + 262144);           //   3145728 B
  short* gxbuf       = (short*)(ws + 4096 + 262144 + 262144 + 3145728); // 201326592 B

  // zero flags + h double-buffers (deterministic across graph replays)
  hipMemsetAsync(ws, 0, 4096 + 262144, stream);

  // 0: w_ih -> bf16
  cvt_wih_kernel<<<768, 256, 0, stream>>>(w_ih, wihb);
  // 1: gx GEMM
  gemm_gx_kernel<<<dim3(24, 256), 256, 0, stream>>>(ids, emb, wihb, gxbuf);
  // 2: persistent scan — 256 WGs x 256 thr (round-7 structure + packed flags +
  //    conflict-free part exchange). All WGs co-resident.
  gru_scan_kernel<<<256, 256, 0, stream>>>(gxbuf, w_hh, b_ih, b_hh, hbuf_q, flags, hsum);
  // 3: projections
  proj_kernel<<<64, 128, 0, stream>>>(hsum, w_mean, b_mean, w_logv, b_logv, out);
}

// Round 12
// 2149.135 us; speedup vs baseline: 4.2093x; 1.2547x over previous
//
#include <hip/hip_runtime.h>
#include <hip/hip_bf16.h>
#include <stdint.h>
#include <stddef.h>

// Problem sizes (fixed)
#define HID   1024
#define NB    64
#define SEQ   512
#define G3    3072   // 3*HID
#define EMB   512
#define LAT   64

typedef __attribute__((ext_vector_type(4))) float f32x4;
typedef __attribute__((ext_vector_type(8))) short bfrag;  // 8 bf16 (4 VGPRs)
typedef unsigned long long ull;

// ---------- helpers ----------
__device__ __forceinline__ unsigned short f2bf(float x) {   // RNE f32->bf16
  union { float f; unsigned u; } v; v.f = x;
  unsigned u = v.u + 0x7fffu + ((v.u >> 16) & 1u);
  return (unsigned short)(u >> 16);
}
__device__ __forceinline__ float bf2f(short s) {
  union { unsigned u; float f; } v; v.u = ((unsigned)(unsigned short)s) << 16;
  return v.f;
}
__device__ __forceinline__ float fsig(float x) {
  return 1.0f / (1.0f + __builtin_exp2f(-1.4426950408889634f * x));
}
__device__ __forceinline__ float ftanh(float x) {
  return 1.0f - 2.0f / (1.0f + __builtin_exp2f(2.8853900817779268f * x));
}
__device__ __forceinline__ void gload_lds16(const void* g, void* l) {
  __builtin_amdgcn_global_load_lds(
      (const __attribute__((address_space(1))) unsigned int*)g,
      (__attribute__((address_space(3))) unsigned int*)l, 16, 0, 0);
}

// ---------- kernel 0: w_ih f32 -> bf16 ----------
__global__ void cvt_wih_kernel(const float* __restrict__ in, short* __restrict__ out) {
  int i = (blockIdx.x * 256 + threadIdx.x) * 8;   // grid sized exactly
  f32x4 a = *(const f32x4*)(in + i);
  f32x4 b = *(const f32x4*)(in + i + 4);
  bfrag o;
  o[0]=(short)f2bf(a[0]); o[1]=(short)f2bf(a[1]); o[2]=(short)f2bf(a[2]); o[3]=(short)f2bf(a[3]);
  o[4]=(short)f2bf(b[0]); o[5]=(short)f2bf(b[1]); o[6]=(short)f2bf(b[2]); o[7]=(short)f2bf(b[3]);
  *(bfrag*)(out + i) = o;
}

// ---------- kernel 1: gx = emb[ids] @ w_ih^T  (bf16 MFMA, fp32 acc, bf16 out) ----------
__global__ void __launch_bounds__(256) gemm_gx_kernel(
    const int* __restrict__ ids, const float* __restrict__ emb,
    const short* __restrict__ wih, short* __restrict__ gx)
{
  const int nt = blockIdx.x, mt = blockIdx.y;
  const int tid = threadIdx.x;
  const int lane = tid & 63, wave = tid >> 6;
  const int wr = wave >> 1, wc = wave & 1;

  __shared__ __align__(16) short A_lds[128 * 48];
  __shared__ __align__(16) short B_lds[128 * 32];
  __shared__ int ids_s[128];

  if (tid < 128) ids_s[tid] = ids[mt * 128 + tid];
  __syncthreads();

  f32x4 acc[4][4];
  #pragma unroll
  for (int i = 0; i < 4; ++i)
    #pragma unroll
    for (int j = 0; j < 4; ++j) acc[i][j] = (f32x4){0.f, 0.f, 0.f, 0.f};

  const int r_stage = tid >> 1;
  const int kh = (tid & 1) * 16;

  #pragma unroll 1
  for (int kc = 0; kc < 16; ++kc) {
    __syncthreads();
    {
      const float* src = emb + (size_t)ids_s[r_stage] * 512 + kc * 32 + kh;
      f32x4 v0 = *(const f32x4*)(src);
      f32x4 v1 = *(const f32x4*)(src + 4);
      f32x4 v2 = *(const f32x4*)(src + 8);
      f32x4 v3 = *(const f32x4*)(src + 12);
      bfrag p0, p1;
      p0[0]=(short)f2bf(v0[0]); p0[1]=(short)f2bf(v0[1]); p0[2]=(short)f2bf(v0[2]); p0[3]=(short)f2bf(v0[3]);
      p0[4]=(short)f2bf(v1[0]); p0[5]=(short)f2bf(v1[1]); p0[6]=(short)f2bf(v1[2]); p0[7]=(short)f2bf(v1[3]);
      p1[0]=(short)f2bf(v2[0]); p1[1]=(short)f2bf(v2[1]); p1[2]=(short)f2bf(v2[2]); p1[3]=(short)f2bf(v2[3]);
      p1[4]=(short)f2bf(v3[0]); p1[5]=(short)f2bf(v3[1]); p1[6]=(short)f2bf(v3[2]); p1[7]=(short)f2bf(v3[3]);
      *(bfrag*)&A_lds[r_stage * 48 + kh]     = p0;
      *(bfrag*)&A_lds[r_stage * 48 + kh + 8] = p1;
    }
    {
      #pragma unroll
      for (int ii = 0; ii < 2; ++ii) {
        int i = wave * 2 + ii;
        const short* src = wih + (size_t)(nt * 128 + i * 16 + (lane >> 2)) * 512
                               + kc * 32 + (lane & 3) * 8;
        gload_lds16((const void*)src, (void*)&B_lds[i * 512]);
      }
    }
    asm volatile("s_waitcnt vmcnt(0)" ::: "memory");
    __syncthreads();

    bfrag a[4], b[4];
    #pragma unroll
    for (int mi = 0; mi < 4; ++mi)
      a[mi] = *(const bfrag*)&A_lds[(wr * 64 + mi * 16 + (lane & 15)) * 48 + (lane >> 4) * 8];
    #pragma unroll
    for (int ni = 0; ni < 4; ++ni)
      b[ni] = *(const bfrag*)&B_lds[(wc * 64 + ni * 16 + (lane & 15)) * 32 + (lane >> 4) * 8];
    #pragma unroll
    for (int mi = 0; mi < 4; ++mi)
      #pragma unroll
      for (int ni = 0; ni < 4; ++ni)
        acc[mi][ni] = __builtin_amdgcn_mfma_f32_16x16x32_bf16(a[mi], b[ni], acc[mi][ni], 0, 0, 0);
  }

  #pragma unroll
  for (int mi = 0; mi < 4; ++mi)
    #pragma unroll
    for (int ni = 0; ni < 4; ++ni)
      #pragma unroll
      for (int r = 0; r < 4; ++r) {
        int m = mt * 128 + wr * 64 + mi * 16 + (lane >> 4) * 4 + r;
        int n = nt * 128 + wc * 64 + ni * 16 + (lane & 15);
        gx[(size_t)m * G3 + n] = (short)f2bf(acc[mi][ni][r]);
      }
}

// ---------- kernel 2: persistent GRU scan (round-7 base + wave-quarter staging + hierarchical poll) ----------
// 256 WGs x 256 thr (4 waves). WG = (team = bid>>6 owns 16 batch rows,
// cg = bid&63 owns 16 hidden cols). Wave = K-quarter (wfrag[3][8] = 96 VGPRs).
// CHANGE 1: wave w stages ONLY its K-quarter (contiguous 1024 exchange qwords,
//   cg in [16w,16w+16)) -> no cross-wave LDS dependency -> S1 barrier deleted.
// CHANGE 2: hierarchical poll — flags stay 64B apart (no store-line sharing);
//   the cg==0 WG of each team aggregates its 64 flags into ONE superflag line;
//   the other 63 WGs poll that single broadcast line (poll fan-out /32).
__global__ void __launch_bounds__(256, 1) gru_scan_kernel(
    const short* __restrict__ gx, const float* __restrict__ whh,
    const float* __restrict__ bihp, const float* __restrict__ bhhp,
    ull* __restrict__ hbuf_q, unsigned int* __restrict__ flags,
    unsigned int* __restrict__ superf, float* __restrict__ hsum)
{
  const int wg   = blockIdx.x;       // 0..255
  const int team = wg >> 6;          // 0..3
  const int cg   = wg & 63;          // col-group
  const int tid  = threadIdx.x;
  const int lane = tid & 63, wave = tid >> 6;   // wave = K-quarter 0..3
  const int bl   = lane & 15;
  const int bsub = (lane >> 4) * 4;
  const int jcol = cg * 16 + bl;
  const int bteam = team * 16;

  __shared__ __align__(16) short h_lds[16 * 1024];   // 32 KB [b][k] swizzled
  __shared__ __align__(16) float part[3 * 3 * 256];  // 9 KB: [g][wave-1][lane*4]
  __shared__ __align__(16) short hstg[256];          // 512 B [b][c] exchange order

  // --- weights: 16 cols x 3 gates x K-quarter as B-frags (bf16), 96 VGPRs ---
  bfrag wfrag[3][8];
  #pragma unroll
  for (int g = 0; g < 3; ++g) {
    const float* wrow = whh + (size_t)(g * 1024 + jcol) * 1024 + wave * 256 + (lane >> 4) * 8;
    #pragma unroll
    for (int ks = 0; ks < 8; ++ks) {
      const float* p = wrow + ks * 32;
      f32x4 lo = *(const f32x4*)p;
      f32x4 hi = *(const f32x4*)(p + 4);
      bfrag f;
      f[0]=(short)f2bf(lo[0]); f[1]=(short)f2bf(lo[1]); f[2]=(short)f2bf(lo[2]); f[3]=(short)f2bf(lo[3]);
      f[4]=(short)f2bf(hi[0]); f[5]=(short)f2bf(hi[1]); f[6]=(short)f2bf(hi[2]); f[7]=(short)f2bf(hi[3]);
      wfrag[g][ks] = f;
    }
  }
  float bih_r[3], bhh_r[3];
  #pragma unroll
  for (int g = 0; g < 3; ++g) {
    bih_r[g] = bihp[g * 1024 + jcol];
    bhh_r[g] = bhhp[g * 1024 + jcol];
  }

  float hprev[4] = {0.f, 0.f, 0.f, 0.f};
  float hacc[4]  = {0.f, 0.f, 0.f, 0.f};
  const int xorm = (bl & 7) << 4;
  const char* lbase = (const char*)h_lds + bl * 2048;
  unsigned int* fteam  = flags + team * 1024;   // 64 flags, 64B (16 u32) apart
  unsigned int* myflag = fteam + cg * 16;
  unsigned int* mysuper = superf + team * 16;   // one 64B line per team
  const bool is_agg = (cg == 0);

  // staging constants: wave w owns exchange qwords [w*1024, w*1024+1024)
  const int st_b  = lane >> 2;        // batch row this lane writes
  const int st_c4 = lane & 3;         // col-quad within cg block
  char* const st_base = (char*)h_lds + st_b * 2048;
  const int st_swz = (st_b & 7) << 4;

  // gx prefetch for current step (wave 0 = combiner)
  short gxr_[4][3];
  if (wave == 0) {
    #pragma unroll
    for (int r = 0; r < 4; ++r) {
      size_t base = ((size_t)(bteam + bsub + r) * SEQ + 0) * G3 + jcol;
      gxr_[r][0] = gx[base];
      gxr_[r][1] = gx[base + 1024];
      gxr_[r][2] = gx[base + 2048];
    }
  }

  #pragma unroll 1
  for (int s = 0; s < SEQ; ++s) {
    const ull* hsrc = hbuf_q + ((s & 1) ? 16384 : 0) + team * 4096;       // 4096 qwords
    ull*       hdst = hbuf_q + (((s + 1) & 1) ? 16384 : 0) + team * 4096;

    // 1. stage THIS WAVE's K-quarter -> LDS (contiguous 1024 qwords, coalesced).
    //    No barrier: each wave reads/writes only its own LDS quarter, and the
    //    MFMA below reads only this wave's quarter (compiler handles lgkmcnt).
    {
      ull hv[16];
      #pragma unroll
      for (int j = 0; j < 16; ++j)
        hv[j] = __hip_atomic_load(hsrc + wave * 1024 + j * 64 + lane,
                                  __ATOMIC_RELAXED, __HIP_MEMORY_SCOPE_AGENT);
      #pragma unroll
      for (int j = 0; j < 16; ++j) {
        int cgq = wave * 16 + j;
        *(ull*)(st_base + (((cgq * 32 + st_c4 * 8)) ^ st_swz)) = hv[j];
      }
    }

    // 2. partial gh over this wave's K-quarter: 24 MFMAs
    f32x4 a0 = {0.f,0.f,0.f,0.f}, a1 = {0.f,0.f,0.f,0.f}, a2 = {0.f,0.f,0.f,0.f};
    #pragma unroll
    for (int ks = 0; ks < 8; ++ks) {
      int k2 = wave * 512 + ks * 64 + (lane >> 4) * 16;   // byte offset of k*2
      bfrag af = *(const bfrag*)(lbase + (k2 ^ xorm));
      a0 = __builtin_amdgcn_mfma_f32_16x16x32_bf16(af, wfrag[0][ks], a0, 0, 0, 0);
      a1 = __builtin_amdgcn_mfma_f32_16x16x32_bf16(af, wfrag[1][ks], a1, 0, 0, 0);
      a2 = __builtin_amdgcn_mfma_f32_16x16x32_bf16(af, wfrag[2][ks], a2, 0, 0, 0);
    }
    if (wave) {
      int w1 = wave - 1;
      *(f32x4*)&part[((0 * 3 + w1) * 64 + lane) * 4] = a0;
      *(f32x4*)&part[((1 * 3 + w1) * 64 + lane) * 4] = a1;
      *(f32x4*)&part[((2 * 3 + w1) * 64 + lane) * 4] = a2;
    }
    __syncthreads();   // S2: partials ready

    // 3. wave 0: combine K-quarters, gates (fp32), stage h_new in LDS
    if (wave == 0) {
      f32x4 s0 = a0, s1 = a1, s2 = a2;
      #pragma unroll
      for (int w1 = 0; w1 < 3; ++w1) {
        s0 += *(const f32x4*)&part[((0 * 3 + w1) * 64 + lane) * 4];
        s1 += *(const f32x4*)&part[((1 * 3 + w1) * 64 + lane) * 4];
        s2 += *(const f32x4*)&part[((2 * 3 + w1) * 64 + lane) * 4];
      }
      #pragma unroll
      for (int r = 0; r < 4; ++r) {
        float ghr = s0[r] + bhh_r[0];
        float ghz = s1[r] + bhh_r[1];
        float ghn = s2[r] + bhh_r[2];
        float rg = fsig(bf2f(gxr_[r][0]) + bih_r[0] + ghr);
        float zg = fsig(bf2f(gxr_[r][1]) + bih_r[1] + ghz);
        float ng = ftanh(bf2f(gxr_[r][2]) + bih_r[2] + rg * ghn);
        float hn = (1.f - zg) * ng + zg * hprev[r];
        hprev[r] = hn;
        hacc[r] += hn;
        hstg[(bsub + r) * 16 + bl] = (short)f2bf(hn);   // exchange order [b][c]
      }
    }
    __syncthreads();   // S3: hstg ready

    // 4. wave 1: ONE contiguous 512B agent burst + drain + flag.
    //    wave 0: prefetch next gx, then poll (aggregator: 64 flags -> superflag;
    //    others: single superflag line).
    if (wave == 1) {
      ull v = ((const ull*)hstg)[lane];
      __hip_atomic_store(hdst + cg * 64 + lane, v, __ATOMIC_RELAXED,
                         __HIP_MEMORY_SCOPE_AGENT);
      asm volatile("s_waitcnt vmcnt(0)" ::: "memory");   // this wave's stores done
      if (lane == 0)
        __hip_atomic_store(myflag, (unsigned)(s + 1), __ATOMIC_RELAXED,
                           __HIP_MEMORY_SCOPE_AGENT);
    }
    if (wave == 0) {
      int sn = (s + 1 < SEQ) ? (s + 1) : s;
      #pragma unroll
      for (int r = 0; r < 4; ++r) {
        size_t base = ((size_t)(bteam + bsub + r) * SEQ + sn) * G3 + jcol;
        gxr_[r][0] = gx[base];
        gxr_[r][1] = gx[base + 1024];
        gxr_[r][2] = gx[base + 2048];
      }
      unsigned tgt = (unsigned)(s + 1);
      if (is_agg) {
        for (;;) {   // aggregator: 64 lanes, one 64B-spread flag each
          unsigned v = __hip_atomic_load(fteam + lane * 16, __ATOMIC_RELAXED,
                                         __HIP_MEMORY_SCOPE_AGENT);
          if (__all((int)(v >= tgt))) break;
        }
        if (lane == 0)
          __hip_atomic_store(mysuper, tgt, __ATOMIC_RELAXED,
                             __HIP_MEMORY_SCOPE_AGENT);
      } else {
        while (__hip_atomic_load(mysuper, __ATOMIC_RELAXED,
                                 __HIP_MEMORY_SCOPE_AGENT) < tgt) { }
      }
    }
    __syncthreads();   // S4
  }

  if (wave == 0) {
    #pragma unroll
    for (int r = 0; r < 4; ++r)
      hsum[(size_t)(bteam + bsub + r) * 1024 + jcol] = hacc[r] * (1.0f / 512.0f);
  }
}

// ---------- kernel 3: mean/logv projections (fp32) ----------
__global__ void proj_kernel(const float* __restrict__ hbar,
                            const float* __restrict__ wm, const float* __restrict__ bm,
                            const float* __restrict__ wl, const float* __restrict__ bl,
                            float* __restrict__ out)
{
  int b = blockIdx.x, t = threadIdx.x;  // 128 threads: 0-63 mean, 64-127 logv
  __shared__ float hrow[1024];
  for (int k = t; k < 1024; k += 128) hrow[k] = hbar[(size_t)b * 1024 + k];
  __syncthreads();
  int j = t & 63;
  const float* w = (t < 64) ? (wm + (size_t)j * 1024) : (wl + (size_t)j * 1024);
  float acc = (t < 64) ? bm[j] : bl[j];
  for (int k = 0; k < 1024; k += 4) {
    f32x4 wv = *(const f32x4*)(w + k);
    acc += hrow[k] * wv[0] + hrow[k+1] * wv[1] + hrow[k+2] * wv[2] + hrow[k+3] * wv[3];
  }
  out[(size_t)((t < 64) ? 0 : 4096) + b * 64 + j] = acc;
}

// ---------- launch ----------
extern "C" void kernel_launch(void* const* d_in, const int* in_sizes, int n_in,
                              void* d_out, int out_size, void* d_ws, size_t ws_size,
                              hipStream_t stream) {
  const int*   ids   = (const int*)d_in[0];
  const float* emb   = (const float*)d_in[1];
  const float* w_ih  = (const float*)d_in[2];
  const float* w_hh  = (const float*)d_in[3];
  const float* b_ih  = (const float*)d_in[4];
  const float* b_hh  = (const float*)d_in[5];
  const float* w_mean= (const float*)d_in[6];
  const float* b_mean= (const float*)d_in[7];
  const float* w_logv= (const float*)d_in[8];
  const float* b_logv= (const float*)d_in[9];
  float* out = (float*)d_out;

  char* ws = (char*)d_ws;
  // ws layout
  unsigned int* superf = (unsigned int*)(ws);                //      1024 B (4 superflags, 64B apart)
  unsigned int* flags  = (unsigned int*)(ws + 1024);         //     16384 B (4 teams x 64 flags, 64B apart)
  ull* hbuf_q        = (ull*)(ws + 1024 + 16384);            //    262144 B [2][4][4096] qwords bf16 ([cg][b][c4])
  float* hsum        = (float*)(ws + 1024 + 16384 + 262144); //    262144 B [64][1024] f32
  short* wihb        = (short*)(ws + 1024 + 16384 + 262144 + 262144);            //   3145728 B
  short* gxbuf       = (short*)(ws + 1024 + 16384 + 262144 + 262144 + 3145728);  // 201326592 B

  // zero superflags + flags + h double-buffers (deterministic across replays)
  hipMemsetAsync(ws, 0, 1024 + 16384 + 262144, stream);

  // 0: w_ih -> bf16
  cvt_wih_kernel<<<768, 256, 0, stream>>>(w_ih, wihb);
  // 1: gx GEMM
  gemm_gx_kernel<<<dim3(24, 256), 256, 0, stream>>>(ids, emb, wihb, gxbuf);
  // 2: persistent scan — 256 WGs x 256 thr (round-7 structure, wave-quarter
  //    staging, hierarchical superflag poll). All WGs co-resident.
  gru_scan_kernel<<<256, 256, 0, stream>>>(gxbuf, w_hh, b_ih, b_hh,
                                           hbuf_q, flags, superf, hsum);
  // 3: projections
  proj_kernel<<<64, 128, 0, stream>>>(hsum, w_mean, b_mean, w_logv, b_logv, out);
}